// Round 4
// baseline (194.590 us; speedup 1.0000x reference)
//
#include <hip/hip_runtime.h>
#include <hip/hip_bf16.h>

#define B_    32
#define CIN_  128
#define H_    64
#define W_    64
#define COUT_ 128
#define NK_   4
#define HID_  32
#define TEMP_ 34.0f

typedef short bf16x8 __attribute__((ext_vector_type(8)));
typedef short short4v __attribute__((ext_vector_type(4)));
typedef float f32x4  __attribute__((ext_vector_type(4)));
typedef float f32x16 __attribute__((ext_vector_type(16)));

__device__ __forceinline__ short f2bf(float f) {
    union { float f; unsigned u; } c; c.f = f;
    unsigned r = (c.u + 0x7FFFu + ((c.u >> 16) & 1u)) >> 16;
    return (short)r;
}
__device__ __forceinline__ float bf2f(short s) {
    union { unsigned u; float f; } c; c.u = ((unsigned)(unsigned short)s) << 16;
    return c.f;
}

// =========== k_prep: transpose x -> bf16 xb[b][h][w][ci] + ctx partial sums ====
#define TPAD 140
__global__ __launch_bounds__(256) void k_prep(const float* __restrict__ x,
                                              float* __restrict__ ctx,
                                              short* __restrict__ xb) {
    __shared__ short T[64 * TPAD];
    const int tid = threadIdx.x;
    const int b = blockIdx.x >> 6;
    const int h = blockIdx.x & 63;
    const int w = tid & 63;
    const int wv = tid >> 6;
    const float* xp = x + (size_t)b * CIN_ * (H_ * W_) + h * W_ + w;
#pragma unroll
    for (int j = 0; j < 8; ++j) {
        const int ci0 = j * 16 + wv * 4;       // 4 consecutive ci per thread
        float v0 = xp[(size_t)(ci0 + 0) * (H_ * W_)];
        float v1 = xp[(size_t)(ci0 + 1) * (H_ * W_)];
        float v2 = xp[(size_t)(ci0 + 2) * (H_ * W_)];
        float v3 = xp[(size_t)(ci0 + 3) * (H_ * W_)];
        short4v sv = { f2bf(v0), f2bf(v1), f2bf(v2), f2bf(v3) };
        *(short4v*)(&T[w * TPAD + ci0]) = sv;
    }
    __syncthreads();
    // ctx partial sums: thread (ci, half) sums 32 w-slots; lane-pair combine
    {
        const int ci = tid >> 1;
        const int ph = tid & 1;
        float s = 0.f;
        for (int ww = ph * 32; ww < ph * 32 + 32; ++ww) s += bf2f(T[ww * TPAD + ci]);
        s += __shfl_down(s, 1, 64);
        if (ph == 0) atomicAdd(&ctx[b * CIN_ + ci], s);
    }
    // coalesced store of transposed tile
    const int ww = tid >> 2;
    const int cc = tid & 3;
    short* op = xb + (((size_t)b * H_ + h) * W_ + ww) * CIN_ + cc * 32;
    const short* tp = &T[ww * TPAD + cc * 32];
#pragma unroll
    for (int k = 0; k < 4; ++k)
        *(bf16x8*)(op + k * 8) = *(const bf16x8*)(tp + k * 8);
}

// =========== k_context (fallback path): direct mean ===========
__global__ void k_context(const float* __restrict__ x, float* __restrict__ ctx) {
    const int bc = blockIdx.x;
    const float* p = x + (size_t)bc * (H_ * W_);
    const int lane = threadIdx.x;
    float s = 0.f;
    for (int i = lane * 4; i < H_ * W_; i += 64 * 4) {
        float4 v = *(const float4*)(p + i);
        s += v.x + v.y + v.z + v.w;
    }
    for (int off = 32; off > 0; off >>= 1) s += __shfl_down(s, off, 64);
    if (lane == 0) ctx[bc] = s * (1.0f / (H_ * W_));
}

// =========== k_att: parallel attention + aggregated bias (1 block x 1024) =====
#define SF1S 129
__global__ __launch_bounds__(1024) void k_att(const float* __restrict__ ctx,
                      const float* __restrict__ fc1w,
                      const float* __restrict__ fc2w,
                      const float* __restrict__ fc2b,
                      const float* __restrict__ bias,
                      float* __restrict__ att, float* __restrict__ aggb,
                      float ctx_scale) {
    __shared__ float sctx[B_ * CIN_];
    __shared__ float sf1[HID_ * SF1S];
    __shared__ float shid[B_ * HID_];
    __shared__ float satt[B_ * NK_];
    const int t = threadIdx.x;
    for (int i = t; i < B_ * CIN_; i += 1024) sctx[i] = ctx[i] * ctx_scale;
    for (int i = t; i < HID_ * CIN_; i += 1024) sf1[(i >> 7) * SF1S + (i & 127)] = fc1w[i];
    __syncthreads();
    {
        const int b = t >> 5, hh = t & 31;
        float s = 0.f;
        for (int ci = 0; ci < CIN_; ++ci) s += sctx[b * CIN_ + ci] * sf1[hh * SF1S + ci];
        shid[b * HID_ + hh] = fmaxf(s, 0.f);
    }
    __syncthreads();
    if (t < B_) {
        float lg[NK_]; float mx = -1e30f;
#pragma unroll
        for (int k = 0; k < NK_; ++k) {
            float s = fc2b[k];
            for (int hh = 0; hh < HID_; ++hh) s += shid[t * HID_ + hh] * fc2w[k * HID_ + hh];
            lg[k] = s / TEMP_; mx = fmaxf(mx, lg[k]);
        }
        float den = 0.f;
#pragma unroll
        for (int k = 0; k < NK_; ++k) { lg[k] = expf(lg[k] - mx); den += lg[k]; }
        const float rd = 1.0f / den;
#pragma unroll
        for (int k = 0; k < NK_; ++k) { satt[t * NK_ + k] = lg[k] * rd; att[t * NK_ + k] = lg[k] * rd; }
    }
    __syncthreads();
    {
        const int b = t >> 5, c0 = (t & 31) * 4;
        float4 bw[NK_];
#pragma unroll
        for (int k = 0; k < NK_; ++k) bw[k] = *(const float4*)(bias + k * COUT_ + c0);
        float4 r = make_float4(0.f, 0.f, 0.f, 0.f);
#pragma unroll
        for (int k = 0; k < NK_; ++k) {
            const float a = satt[b * NK_ + k];
            r.x += a * bw[k].x; r.y += a * bw[k].y; r.z += a * bw[k].z; r.w += a * bw[k].w;
        }
        *(float4*)(aggb + b * COUT_ + c0) = r;
    }
}

// =========== k_aggw: aggregate weights -> bf16 [b][co][r][ci] ===========
__global__ void k_aggw(const float* __restrict__ att,
                       const float* __restrict__ weight,
                       short* __restrict__ aggwt) {
    const int idx = blockIdx.x * 256 + threadIdx.x;
    const int ci = idx & 127;
    const int co = (idx >> 7) & 127;
    const int b  = idx >> 14;
    const float a0 = att[b * NK_ + 0];
    const float a1 = att[b * NK_ + 1];
    const float a2 = att[b * NK_ + 2];
    const float a3 = att[b * NK_ + 3];
    const float* w0 = weight + ((size_t)co * CIN_ + ci) * 9;
    const float* w1 = w0 + (size_t)COUT_ * CIN_ * 9;
    const float* w2 = w1 + (size_t)COUT_ * CIN_ * 9;
    const float* w3 = w2 + (size_t)COUT_ * CIN_ * 9;
    short* o = aggwt + ((size_t)(b * COUT_ + co) * 9) * CIN_ + ci;
#pragma unroll
    for (int r = 0; r < 9; ++r)
        o[r * CIN_] = f2bf(a0 * w0[r] + a1 * w1[r] + a2 * w2[r] + a3 * w3[r]);
}

// =========== k_conv: DMA-staged implicit GEMM, 32x32x16 MFMA ===========
// Block = (b, 2 h-rows). LDS: 4 rows x 66 slots x 8 chunks(16B) = 33792 B.
// Swizzle: data (w, ci8') stored at chunk p = (ci8' + w) & 7 of slot w+1
// (coefficient 1 -> reads spread over all 8 bank groups; round-3's coeff 2
//  hit only 4 groups = 8-way conflict, +8 cyc per ds_read_b128).
#define RCH 528
#define RBY 8448
__global__ __launch_bounds__(256, 4) void k_conv(const short* __restrict__ xb,
        const short* __restrict__ aggwt, const float* __restrict__ aggb,
        float* __restrict__ out) {
    __shared__ short xt[4 * RCH * 8];
    const int tid = threadIdx.x;
    const int blk = blockIdx.x;
    const int b = blk & 31;                 // all 32 blocks of b on XCD b&7
    const int h0 = (blk >> 5) * 2;
    const int lane = tid & 63;
    const int wv = tid >> 6;
    const int l31 = lane & 31;
    const int lane5 = lane >> 5;

    const int in_h = h0 - 1 + wv;           // wave wv stages row wv
    const bool valid = (in_h >= 0) && (in_h < H_);
    short* rowp = &xt[wv * (RBY / 2)];
    if (!valid) {
        for (int j = 0; j < 9; ++j) {
            const int idx = j * 64 + lane;
            if (idx < RCH) *(int4*)(&rowp[idx * 8]) = make_int4(0, 0, 0, 0);
        }
    } else if (lane < 16) {                 // halo slots 0 (chunks 0..7) and 65 (520..527)
        const int cl = (lane < 8) ? lane : (512 + lane);
        *(int4*)(&rowp[cl * 8]) = make_int4(0, 0, 0, 0);
    }

    f32x16 acc[4];
#pragma unroll
    for (int nt = 0; nt < 4; ++nt)
#pragma unroll
        for (int k = 0; k < 16; ++k) acc[nt][k] = 0.f;

    const short* Ap = aggwt + (size_t)(b * COUT_ + wv * 32 + l31) * 9 * CIN_ + lane5 * 8;

    for (int half = 0; half < 2; ++half) {
        if (valid) {
            const size_t gband = ((size_t)b * H_ + in_h) * W_;
#pragma unroll
            for (int j = 0; j < 8; ++j) {
                const int cl = 8 + j * 64 + lane;          // linear chunk 8..519
                const int s = cl >> 3;
                const int p = cl & 7;
                const int wp = s - 1;
                const int ci8 = half * 8 + ((p - wp) & 7); // inverse of p=(ci8'+w)&7
                const short* gp = xb + (gband + wp) * CIN_ + ci8 * 8;
                __builtin_amdgcn_global_load_lds(
                    (const __attribute__((address_space(1))) void*)gp,
                    (__attribute__((address_space(3))) void*)(rowp + (8 + j * 64) * 8),
                    16, 0, 0);
            }
        }
        __syncthreads();

#pragma unroll
        for (int kcl = 0; kcl < 4; ++kcl) {
            const int kc = half * 4 + kcl;
            // per-lane B base addrs: i = n32 half (0/32), kw = 0..2
            int SB[2][3];
#pragma unroll
            for (int i = 0; i < 2; ++i)
#pragma unroll
                for (int kw = 0; kw < 3; ++kw) {
                    const int s = i * 32 + l31 + kw;
                    SB[i][kw] = s * 128 + 16 * ((2 * kcl + lane5 + s - 1) & 7);
                }
#pragma unroll
            for (int r = 0; r < 9; ++r) {
                const int kh = r / 3, kw = r % 3;
                bf16x8 av = *(const bf16x8*)(Ap + kc * 16 + r * CIN_);
#pragma unroll
                for (int nt = 0; nt < 4; ++nt) {
                    const char* bp = (const char*)xt + SB[nt & 1][kw] + ((nt >> 1) + kh) * RBY;
                    bf16x8 bv = *(const bf16x8*)bp;
                    acc[nt] = __builtin_amdgcn_mfma_f32_32x32x16_bf16(av, bv, acc[nt], 0, 0, 0);
                }
            }
        }
        if (half == 0) __syncthreads();     // drain readers before restaging
    }

    const float* ab = aggb + b * COUT_;
#pragma unroll
    for (int nt = 0; nt < 4; ++nt) {
        const int hh = h0 + (nt >> 1);
        const int w = (nt & 1) * 32 + l31;
        float* op = out + ((size_t)b * COUT_ * H_ + hh) * W_ + w;
#pragma unroll
        for (int reg = 0; reg < 16; ++reg) {
            const int co = wv * 32 + (reg & 3) + 8 * (reg >> 2) + 4 * lane5;
            op[(size_t)co * (H_ * W_)] = acc[nt][reg] + ab[co];
        }
    }
}

// =========== fallback conv (round-2 proven): in-kernel f32->bf16 staging ======
#define LDS_S 136
__global__ __launch_bounds__(256) void k_conv_fb(const float* __restrict__ x,
                                              const short* __restrict__ aggwt,
                                              const float* __restrict__ aggb,
                                              float* __restrict__ out) {
    __shared__ short xs[3 * 66 * LDS_S];
    const int tid = threadIdx.x;
    const int b = blockIdx.x >> 6;
    const int h = blockIdx.x & 63;
    for (int i = tid; i < 3 * 32 * 16; i += 256) {
        const int hr  = i >> 9;
        const int rem = i & 511;
        const int ci4 = rem >> 4;
        const int wb  = rem & 15;
        const int ih = h + hr - 1;
        float4 v0 = make_float4(0.f, 0.f, 0.f, 0.f), v1 = v0, v2 = v0, v3 = v0;
        if (ih >= 0 && ih < H_) {
            const float* base = x + (((size_t)b * CIN_ + ci4 * 4) * H_ + ih) * W_ + wb * 4;
            v0 = *(const float4*)(base);
            v1 = *(const float4*)(base + H_ * W_);
            v2 = *(const float4*)(base + 2 * H_ * W_);
            v3 = *(const float4*)(base + 3 * H_ * W_);
        }
        short* p = &xs[(hr * 66 + 1 + wb * 4) * LDS_S + ci4 * 4];
        short4v s0 = { f2bf(v0.x), f2bf(v1.x), f2bf(v2.x), f2bf(v3.x) };
        short4v s1 = { f2bf(v0.y), f2bf(v1.y), f2bf(v2.y), f2bf(v3.y) };
        short4v s2 = { f2bf(v0.z), f2bf(v1.z), f2bf(v2.z), f2bf(v3.z) };
        short4v s3 = { f2bf(v0.w), f2bf(v1.w), f2bf(v2.w), f2bf(v3.w) };
        *(short4v*)(p + 0 * LDS_S) = s0;
        *(short4v*)(p + 1 * LDS_S) = s1;
        *(short4v*)(p + 2 * LDS_S) = s2;
        *(short4v*)(p + 3 * LDS_S) = s3;
        short4v z = { 0, 0, 0, 0 };
        if (wb == 0)  *(short4v*)(&xs[(hr * 66 + 0) * LDS_S + ci4 * 4]) = z;
        if (wb == 15) *(short4v*)(&xs[(hr * 66 + 65) * LDS_S + ci4 * 4]) = z;
    }
    __syncthreads();
    const int lane = tid & 63;
    const int wave = tid >> 6;
    const int quad = lane >> 4;
    const int l16  = lane & 15;
    f32x4 acc[2][4];
#pragma unroll
    for (int i = 0; i < 2; ++i)
#pragma unroll
        for (int j = 0; j < 4; ++j) acc[i][j] = (f32x4){0.f, 0.f, 0.f, 0.f};
    const short* A0 = aggwt + (size_t)(b * COUT_ + wave * 32 + l16) * 9 * CIN_;
    const short* A1 = A0 + 16 * 9 * CIN_;
    for (int r = 0; r < 9; ++r) {
        const int kh = r / 3, kw = r % 3;
#pragma unroll
        for (int c = 0; c < 4; ++c) {
            const int k0 = c * 32 + quad * 8;
            bf16x8 a0 = *(const bf16x8*)(A0 + r * CIN_ + k0);
            bf16x8 a1 = *(const bf16x8*)(A1 + r * CIN_ + k0);
#pragma unroll
            for (int nt = 0; nt < 4; ++nt) {
                const int col = nt * 16 + l16 + kw;
                bf16x8 bv = *(const bf16x8*)(&xs[(kh * 66 + col) * LDS_S + k0]);
                acc[0][nt] = __builtin_amdgcn_mfma_f32_16x16x32_bf16(a0, bv, acc[0][nt], 0, 0, 0);
                acc[1][nt] = __builtin_amdgcn_mfma_f32_16x16x32_bf16(a1, bv, acc[1][nt], 0, 0, 0);
            }
        }
    }
    float* outb = out + (size_t)b * COUT_ * H_ * W_ + h * W_;
    const float* ab = aggb + b * COUT_;
#pragma unroll
    for (int mt = 0; mt < 2; ++mt)
#pragma unroll
        for (int rr = 0; rr < 4; ++rr) {
            const int co = wave * 32 + mt * 16 + quad * 4 + rr;
            const float bb = ab[co];
#pragma unroll
            for (int nt = 0; nt < 4; ++nt)
                outb[(size_t)co * (H_ * W_) + nt * 16 + l16] = acc[mt][nt][rr] + bb;
        }
}

extern "C" void kernel_launch(void* const* d_in, const int* in_sizes, int n_in,
                              void* d_out, int out_size, void* d_ws, size_t ws_size,
                              hipStream_t stream) {
    const float* x    = (const float*)d_in[0];
    const float* fc1w = (const float*)d_in[1];
    const float* fc2w = (const float*)d_in[2];
    const float* fc2b = (const float*)d_in[3];
    const float* wgt  = (const float*)d_in[4];
    const float* bias = (const float*)d_in[5];
    float* out = (float*)d_out;

    char* ws = (char*)d_ws;
    float* ctx   = (float*)(ws + 0);            // 16 KB
    float* att   = (float*)(ws + 16384);        // 512 B
    float* aggb  = (float*)(ws + 16896);        // 16 KB
    short* aggwt = (short*)(ws + 65536);        // 9,437,184 B
    short* xb    = (short*)(ws + 9502720);      // 33,554,432 B (bf16)
    const size_t NEED = 9502720u + 33554432u;

    if (ws_size >= NEED) {
        hipMemsetAsync(ctx, 0, B_ * CIN_ * sizeof(float), stream);
        k_prep<<<dim3(B_ * H_), dim3(256), 0, stream>>>(x, ctx, xb);
        k_att<<<dim3(1), dim3(1024), 0, stream>>>(ctx, fc1w, fc2w, fc2b, bias, att, aggb,
                                                  1.0f / (H_ * W_));
        k_aggw<<<dim3((B_ * COUT_ * CIN_) / 256), dim3(256), 0, stream>>>(att, wgt, aggwt);
        k_conv<<<dim3(B_ * (H_ / 2)), dim3(256), 0, stream>>>(xb, aggwt, aggb, out);
    } else {
        k_context<<<dim3(B_ * CIN_), dim3(64), 0, stream>>>(x, ctx);
        k_att<<<dim3(1), dim3(1024), 0, stream>>>(ctx, fc1w, fc2w, fc2b, bias, att, aggb, 1.0f);
        k_aggw<<<dim3((B_ * COUT_ * CIN_) / 256), dim3(256), 0, stream>>>(att, wgt, aggwt);
        k_conv_fb<<<dim3(B_ * H_), dim3(256), 0, stream>>>(x, aggwt, aggb, out);
    }
}

// Round 5
// 192.531 us; speedup vs baseline: 1.0107x; 1.0107x over previous
//
#include <hip/hip_runtime.h>
#include <hip/hip_bf16.h>

#define B_    32
#define CIN_  128
#define H_    64
#define W_    64
#define COUT_ 128
#define NK_   4
#define HID_  32
#define TEMP_ 34.0f

typedef short bf16x8 __attribute__((ext_vector_type(8)));
typedef short short4v __attribute__((ext_vector_type(4)));
typedef float f32x4  __attribute__((ext_vector_type(4)));
typedef float f32x16 __attribute__((ext_vector_type(16)));

__device__ __forceinline__ short f2bf(float f) {
    union { float f; unsigned u; } c; c.f = f;
    unsigned r = (c.u + 0x7FFFu + ((c.u >> 16) & 1u)) >> 16;
    return (short)r;
}
__device__ __forceinline__ float bf2f(short s) {
    union { unsigned u; float f; } c; c.u = ((unsigned)(unsigned short)s) << 16;
    return c.f;
}

// =========== k_prep: transpose x -> bf16 xb[b][h][w][ci] + ctx partial sums ====
#define TPAD 140
__global__ __launch_bounds__(256) void k_prep(const float* __restrict__ x,
                                              float* __restrict__ ctx,
                                              short* __restrict__ xb) {
    __shared__ short T[64 * TPAD];
    const int tid = threadIdx.x;
    const int b = blockIdx.x >> 6;
    const int h = blockIdx.x & 63;
    // float4 loads: thread (k) handles ci = idx>>4, w quad = idx&15
#pragma unroll
    for (int k = 0; k < 8; ++k) {
        const int idx = k * 256 + tid;
        const int wq = idx & 15;
        const int ci = idx >> 4;
        float4 v = *(const float4*)(x + (((size_t)b * CIN_ + ci) * H_ + h) * W_ + wq * 4);
        short* p = &T[(wq * 4) * TPAD + ci];
        p[0 * TPAD] = f2bf(v.x);
        p[1 * TPAD] = f2bf(v.y);
        p[2 * TPAD] = f2bf(v.z);
        p[3 * TPAD] = f2bf(v.w);
    }
    __syncthreads();
    // ctx partial sums: thread (ci, half) sums 32 w-slots; lane-pair combine
    {
        const int ci = tid >> 1;
        const int ph = tid & 1;
        float s = 0.f;
        for (int ww = ph * 32; ww < ph * 32 + 32; ++ww) s += bf2f(T[ww * TPAD + ci]);
        s += __shfl_down(s, 1, 64);
        if (ph == 0) atomicAdd(&ctx[b * CIN_ + ci], s);
    }
    // coalesced store of transposed tile
    const int ww = tid >> 2;
    const int cc = tid & 3;
    short* op = xb + (((size_t)b * H_ + h) * W_ + ww) * CIN_ + cc * 32;
    const short* tp = &T[ww * TPAD + cc * 32];
#pragma unroll
    for (int k = 0; k < 4; ++k)
        *(bf16x8*)(op + k * 8) = *(const bf16x8*)(tp + k * 8);
}

// =========== k_context (fallback path): direct mean ===========
__global__ void k_context(const float* __restrict__ x, float* __restrict__ ctx) {
    const int bc = blockIdx.x;
    const float* p = x + (size_t)bc * (H_ * W_);
    const int lane = threadIdx.x;
    float s = 0.f;
    for (int i = lane * 4; i < H_ * W_; i += 64 * 4) {
        float4 v = *(const float4*)(p + i);
        s += v.x + v.y + v.z + v.w;
    }
    for (int off = 32; off > 0; off >>= 1) s += __shfl_down(s, off, 64);
    if (lane == 0) ctx[bc] = s * (1.0f / (H_ * W_));
}

// =========== k_att: parallel attention + aggregated bias (1 block x 1024) =====
#define SF1S 129
__global__ __launch_bounds__(1024) void k_att(const float* __restrict__ ctx,
                      const float* __restrict__ fc1w,
                      const float* __restrict__ fc2w,
                      const float* __restrict__ fc2b,
                      const float* __restrict__ bias,
                      float* __restrict__ att, float* __restrict__ aggb,
                      float ctx_scale) {
    __shared__ float sctx[B_ * CIN_];
    __shared__ float sf1[HID_ * SF1S];
    __shared__ float shid[B_ * HID_];
    __shared__ float satt[B_ * NK_];
    const int t = threadIdx.x;
    for (int i = t; i < B_ * CIN_; i += 1024) sctx[i] = ctx[i] * ctx_scale;
    for (int i = t; i < HID_ * CIN_; i += 1024) sf1[(i >> 7) * SF1S + (i & 127)] = fc1w[i];
    __syncthreads();
    {
        const int b = t >> 5, hh = t & 31;
        float s = 0.f;
        for (int ci = 0; ci < CIN_; ++ci) s += sctx[b * CIN_ + ci] * sf1[hh * SF1S + ci];
        shid[b * HID_ + hh] = fmaxf(s, 0.f);
    }
    __syncthreads();
    if (t < B_) {
        float lg[NK_]; float mx = -1e30f;
#pragma unroll
        for (int k = 0; k < NK_; ++k) {
            float s = fc2b[k];
            for (int hh = 0; hh < HID_; ++hh) s += shid[t * HID_ + hh] * fc2w[k * HID_ + hh];
            lg[k] = s / TEMP_; mx = fmaxf(mx, lg[k]);
        }
        float den = 0.f;
#pragma unroll
        for (int k = 0; k < NK_; ++k) { lg[k] = expf(lg[k] - mx); den += lg[k]; }
        const float rd = 1.0f / den;
#pragma unroll
        for (int k = 0; k < NK_; ++k) { satt[t * NK_ + k] = lg[k] * rd; att[t * NK_ + k] = lg[k] * rd; }
    }
    __syncthreads();
    {
        const int b = t >> 5, c0 = (t & 31) * 4;
        float4 bw[NK_];
#pragma unroll
        for (int k = 0; k < NK_; ++k) bw[k] = *(const float4*)(bias + k * COUT_ + c0);
        float4 r = make_float4(0.f, 0.f, 0.f, 0.f);
#pragma unroll
        for (int k = 0; k < NK_; ++k) {
            const float a = satt[b * NK_ + k];
            r.x += a * bw[k].x; r.y += a * bw[k].y; r.z += a * bw[k].z; r.w += a * bw[k].w;
        }
        *(float4*)(aggb + b * COUT_ + c0) = r;
    }
}

// =========== k_aggw: aggregate weights -> bf16 [b][co][r][ci] ===========
__global__ void k_aggw(const float* __restrict__ att,
                       const float* __restrict__ weight,
                       short* __restrict__ aggwt) {
    const int idx = blockIdx.x * 256 + threadIdx.x;
    const int ci = idx & 127;
    const int co = (idx >> 7) & 127;
    const int b  = idx >> 14;
    const float a0 = att[b * NK_ + 0];
    const float a1 = att[b * NK_ + 1];
    const float a2 = att[b * NK_ + 2];
    const float a3 = att[b * NK_ + 3];
    const float* w0 = weight + ((size_t)co * CIN_ + ci) * 9;
    const float* w1 = w0 + (size_t)COUT_ * CIN_ * 9;
    const float* w2 = w1 + (size_t)COUT_ * CIN_ * 9;
    const float* w3 = w2 + (size_t)COUT_ * CIN_ * 9;
    short* o = aggwt + ((size_t)(b * COUT_ + co) * 9) * CIN_ + ci;
#pragma unroll
    for (int r = 0; r < 9; ++r)
        o[r * CIN_] = f2bf(a0 * w0[r] + a1 * w1[r] + a2 * w2[r] + a3 * w3[r]);
}

// =========== k_conv: 4-row blocks, B-register-reuse, A-in-regs ===========
// Block = (b, 4 h-rows). LDS: 6 input rows x 66 slots x 8 chunks(16B) = 50688 B.
// Swizzle: data (w, ci8') at chunk p = (ci8' + w) & 7 of slot w+1.
// Inner loop over INPUT row ir: read 6 B-frags once, feed all (or, kh=ir-or).
#define RBY 8448            // bytes per LDS row (66 slots * 128 B)
#define RSH 4224            // shorts per LDS row
__global__ __launch_bounds__(256, 2) void k_conv(const short* __restrict__ xb,
        const short* __restrict__ aggwt, const float* __restrict__ aggb,
        float* __restrict__ out) {
    __shared__ short xt[6 * RSH];
    const int tid = threadIdx.x;
    const int blk = blockIdx.x;
    const int b = blk & 31;                 // all 16 blocks of b on XCD b&7
    const int h0 = (blk >> 5) * 4;
    const int lane = tid & 63;
    const int wv = tid >> 6;
    const int l31 = lane & 31;
    const int lane5 = lane >> 5;

    // zero halo slots (slot 0 and slot 65 of each of 6 rows) - written once
    if (tid < 96) {
        const int row = tid >> 4;
        const int q = tid & 15;
        const int cl = (q < 8) ? q : (512 + q);
        *(int4*)(&xt[row * RSH + cl * 8]) = make_int4(0, 0, 0, 0);
    }

    f32x16 acc[8];
#pragma unroll
    for (int t = 0; t < 8; ++t)
#pragma unroll
        for (int k = 0; k < 16; ++k) acc[t][k] = 0.f;

    const short* Ap = aggwt + (size_t)(b * COUT_ + wv * 32 + l31) * 9 * CIN_ + lane5 * 8;

    for (int half = 0; half < 2; ++half) {
        // stage 6 rows (ci-half), 3072 chunks, 12 DMA/thread
#pragma unroll
        for (int k = 0; k < 12; ++k) {
            const int cbase = k * 256 + wv * 64;      // wave-uniform
            const int row = cbase >> 9;
            const int clb = (cbase & 511) + 8;
            const int in_h = h0 - 1 + row;
            short* dst = &xt[row * RSH + clb * 8];    // wave-uniform base
            if (in_h >= 0 && in_h < H_) {
                const int cl = clb + lane;
                const int s = cl >> 3;
                const int p = cl & 7;
                const int wp = s - 1;
                const int ci8 = half * 8 + ((p - wp) & 7);
                const short* gp = xb + (((size_t)b * H_ + in_h) * W_ + wp) * CIN_ + ci8 * 8;
                __builtin_amdgcn_global_load_lds(
                    (const __attribute__((address_space(1))) void*)gp,
                    (__attribute__((address_space(3))) void*)dst, 16, 0, 0);
            } else {
                *(int4*)(dst + lane * 8) = make_int4(0, 0, 0, 0);
            }
        }
        __syncthreads();

#pragma unroll
        for (int kcl = 0; kcl < 4; ++kcl) {
            const int kc = half * 4 + kcl;
            bf16x8 av[9];
#pragma unroll
            for (int r = 0; r < 9; ++r)
                av[r] = *(const bf16x8*)(Ap + kc * 16 + r * CIN_);
#pragma unroll
            for (int ir = 0; ir < 6; ++ir) {
                bf16x8 bv[2][3];
#pragma unroll
                for (int i = 0; i < 2; ++i)
#pragma unroll
                    for (int kw = 0; kw < 3; ++kw) {
                        const int s = i * 32 + l31 + kw;
                        const int off = 16 * ((2 * kcl + lane5 + s - 1) & 7);
                        bv[i][kw] = *(const bf16x8*)((const char*)xt + ir * RBY + s * 128 + off);
                    }
#pragma unroll
                for (int orr = 0; orr < 4; ++orr) {
                    if (orr <= ir && ir <= orr + 2) {
                        const int kh = ir - orr;
#pragma unroll
                        for (int i = 0; i < 2; ++i)
#pragma unroll
                            for (int kw = 0; kw < 3; ++kw)
                                acc[orr * 2 + i] = __builtin_amdgcn_mfma_f32_32x32x16_bf16(
                                    av[kh * 3 + kw], bv[i][kw], acc[orr * 2 + i], 0, 0, 0);
                    }
                }
            }
        }
        if (half == 0) __syncthreads();     // drain readers before restaging
    }

    const float* ab = aggb + b * COUT_;
#pragma unroll
    for (int orr = 0; orr < 4; ++orr) {
#pragma unroll
        for (int i = 0; i < 2; ++i) {
            const int hh = h0 + orr;
            const int w = i * 32 + l31;
            float* op = out + ((size_t)b * COUT_ * H_ + hh) * W_ + w;
            const f32x16 a = acc[orr * 2 + i];
#pragma unroll
            for (int reg = 0; reg < 16; ++reg) {
                const int co = wv * 32 + (reg & 3) + 8 * (reg >> 2) + 4 * lane5;
                op[(size_t)co * (H_ * W_)] = a[reg] + ab[co];
            }
        }
    }
}

// =========== fallback conv (round-2 proven): in-kernel f32->bf16 staging ======
#define LDS_S 136
__global__ __launch_bounds__(256) void k_conv_fb(const float* __restrict__ x,
                                              const short* __restrict__ aggwt,
                                              const float* __restrict__ aggb,
                                              float* __restrict__ out) {
    __shared__ short xs[3 * 66 * LDS_S];
    const int tid = threadIdx.x;
    const int b = blockIdx.x >> 6;
    const int h = blockIdx.x & 63;
    for (int i = tid; i < 3 * 32 * 16; i += 256) {
        const int hr  = i >> 9;
        const int rem = i & 511;
        const int ci4 = rem >> 4;
        const int wb  = rem & 15;
        const int ih = h + hr - 1;
        float4 v0 = make_float4(0.f, 0.f, 0.f, 0.f), v1 = v0, v2 = v0, v3 = v0;
        if (ih >= 0 && ih < H_) {
            const float* base = x + (((size_t)b * CIN_ + ci4 * 4) * H_ + ih) * W_ + wb * 4;
            v0 = *(const float4*)(base);
            v1 = *(const float4*)(base + H_ * W_);
            v2 = *(const float4*)(base + 2 * H_ * W_);
            v3 = *(const float4*)(base + 3 * H_ * W_);
        }
        short* p = &xs[(hr * 66 + 1 + wb * 4) * LDS_S + ci4 * 4];
        short4v s0 = { f2bf(v0.x), f2bf(v1.x), f2bf(v2.x), f2bf(v3.x) };
        short4v s1 = { f2bf(v0.y), f2bf(v1.y), f2bf(v2.y), f2bf(v3.y) };
        short4v s2 = { f2bf(v0.z), f2bf(v1.z), f2bf(v2.z), f2bf(v3.z) };
        short4v s3 = { f2bf(v0.w), f2bf(v1.w), f2bf(v2.w), f2bf(v3.w) };
        *(short4v*)(p + 0 * LDS_S) = s0;
        *(short4v*)(p + 1 * LDS_S) = s1;
        *(short4v*)(p + 2 * LDS_S) = s2;
        *(short4v*)(p + 3 * LDS_S) = s3;
        short4v z = { 0, 0, 0, 0 };
        if (wb == 0)  *(short4v*)(&xs[(hr * 66 + 0) * LDS_S + ci4 * 4]) = z;
        if (wb == 15) *(short4v*)(&xs[(hr * 66 + 65) * LDS_S + ci4 * 4]) = z;
    }
    __syncthreads();
    const int lane = tid & 63;
    const int wave = tid >> 6;
    const int quad = lane >> 4;
    const int l16  = lane & 15;
    f32x4 acc[2][4];
#pragma unroll
    for (int i = 0; i < 2; ++i)
#pragma unroll
        for (int j = 0; j < 4; ++j) acc[i][j] = (f32x4){0.f, 0.f, 0.f, 0.f};
    const short* A0 = aggwt + (size_t)(b * COUT_ + wave * 32 + l16) * 9 * CIN_;
    const short* A1 = A0 + 16 * 9 * CIN_;
    for (int r = 0; r < 9; ++r) {
        const int kh = r / 3, kw = r % 3;
#pragma unroll
        for (int c = 0; c < 4; ++c) {
            const int k0 = c * 32 + quad * 8;
            bf16x8 a0 = *(const bf16x8*)(A0 + r * CIN_ + k0);
            bf16x8 a1 = *(const bf16x8*)(A1 + r * CIN_ + k0);
#pragma unroll
            for (int nt = 0; nt < 4; ++nt) {
                const int col = nt * 16 + l16 + kw;
                bf16x8 bv = *(const bf16x8*)(&xs[(kh * 66 + col) * LDS_S + k0]);
                acc[0][nt] = __builtin_amdgcn_mfma_f32_16x16x32_bf16(a0, bv, acc[0][nt], 0, 0, 0);
                acc[1][nt] = __builtin_amdgcn_mfma_f32_16x16x32_bf16(a1, bv, acc[1][nt], 0, 0, 0);
            }
        }
    }
    float* outb = out + (size_t)b * COUT_ * H_ * W_ + h * W_;
    const float* ab = aggb + b * COUT_;
#pragma unroll
    for (int mt = 0; mt < 2; ++mt)
#pragma unroll
        for (int rr = 0; rr < 4; ++rr) {
            const int co = wave * 32 + mt * 16 + quad * 4 + rr;
            const float bb = ab[co];
#pragma unroll
            for (int nt = 0; nt < 4; ++nt)
                outb[(size_t)co * (H_ * W_) + nt * 16 + l16] = acc[mt][nt][rr] + bb;
        }
}

extern "C" void kernel_launch(void* const* d_in, const int* in_sizes, int n_in,
                              void* d_out, int out_size, void* d_ws, size_t ws_size,
                              hipStream_t stream) {
    const float* x    = (const float*)d_in[0];
    const float* fc1w = (const float*)d_in[1];
    const float* fc2w = (const float*)d_in[2];
    const float* fc2b = (const float*)d_in[3];
    const float* wgt  = (const float*)d_in[4];
    const float* bias = (const float*)d_in[5];
    float* out = (float*)d_out;

    char* ws = (char*)d_ws;
    float* ctx   = (float*)(ws + 0);            // 16 KB
    float* att   = (float*)(ws + 16384);        // 512 B
    float* aggb  = (float*)(ws + 16896);        // 16 KB
    short* aggwt = (short*)(ws + 65536);        // 9,437,184 B
    short* xb    = (short*)(ws + 9502720);      // 33,554,432 B (bf16)
    const size_t NEED = 9502720u + 33554432u;

    if (ws_size >= NEED) {
        hipMemsetAsync(ctx, 0, B_ * CIN_ * sizeof(float), stream);
        k_prep<<<dim3(B_ * H_), dim3(256), 0, stream>>>(x, ctx, xb);
        k_att<<<dim3(1), dim3(1024), 0, stream>>>(ctx, fc1w, fc2w, fc2b, bias, att, aggb,
                                                  1.0f / (H_ * W_));
        k_aggw<<<dim3((B_ * COUT_ * CIN_) / 256), dim3(256), 0, stream>>>(att, wgt, aggwt);
        k_conv<<<dim3(B_ * (H_ / 4)), dim3(256), 0, stream>>>(xb, aggwt, aggb, out);
    } else {
        k_context<<<dim3(B_ * CIN_), dim3(64), 0, stream>>>(x, ctx);
        k_att<<<dim3(1), dim3(1024), 0, stream>>>(ctx, fc1w, fc2w, fc2b, bias, att, aggb, 1.0f);
        k_aggw<<<dim3((B_ * COUT_ * CIN_) / 256), dim3(256), 0, stream>>>(att, wgt, aggwt);
        k_conv_fb<<<dim3(B_ * H_), dim3(256), 0, stream>>>(x, aggwt, aggb, out);
    }
}